// Round 12
// baseline (389.549 us; speedup 1.0000x reference)
//
#include <hip/hip_runtime.h>

#define HH 512
#define WW 512
#define BB 8
#define IMG (HH*WW)
#define NTOT (BB*IMG)

typedef float f32x4 __attribute__((ext_vector_type(4)));
typedef _Float16 half8 __attribute__((ext_vector_type(8)));

__device__ inline uint f2h2(float a, float b) {
  uint d; asm("v_cvt_pkrtz_f16_f32 %0, %1, %2" : "=v"(d) : "v"(a), "v"(b)); return d;
}
__device__ inline uint pkfma(uint a, uint b, uint c) {
  uint d; asm("v_pk_fma_f16 %0, %1, %2, %3" : "=v"(d) : "v"(a), "v"(b), "v"(c)); return d;
}
__device__ inline uint pkmax0(uint a) {
  uint d, z = 0u; asm("v_pk_max_f16 %0, %1, %2" : "=v"(d) : "v"(a), "v"(z)); return d;
}

__device__ inline void atomic_block_sum(float part, float* red, float* dst) {
  for (int off = 32; off > 0; off >>= 1) part += __shfl_down(part, off, 64);
  int lane = threadIdx.x & 63, w = threadIdx.x >> 6;
  if (lane == 0) red[w] = part;
  __syncthreads();
  if (threadIdx.x == 0) atomicAdd(dst, red[0] + red[1] + red[2] + red[3]);
}

__device__ inline void reduce3_atomic(float a, float b, float c, float* red,
                                      float* da, float* db, float* dc) {
  for (int off = 32; off > 0; off >>= 1) {
    a += __shfl_down(a, off, 64);
    b += __shfl_down(b, off, 64);
    c += __shfl_down(c, off, 64);
  }
  int lane = threadIdx.x & 63, w = threadIdx.x >> 6;
  if (lane == 0) { red[w*3] = a; red[w*3+1] = b; red[w*3+2] = c; }
  __syncthreads();
  if (threadIdx.x == 0) {
    atomicAdd(da, red[0]+red[3]+red[6]+red[9]);
    if (db) atomicAdd(db, red[1]+red[4]+red[7]+red[10]);
    if (dc) atomicAdd(dc, red[2]+red[5]+red[8]+red[11]);
  }
}

// device-scope grid barrier: monotone counter, all 512 blocks resident (verified host-side)
__device__ inline void gbar(uint* cnt, uint target) {
  __syncthreads();
  if (threadIdx.x == 0) {
    __threadfence();   // release own stores
    __hip_atomic_fetch_add(cnt, 1u, __ATOMIC_ACQ_REL, __HIP_MEMORY_SCOPE_AGENT);
    while (__hip_atomic_load(cnt, __ATOMIC_ACQUIRE, __HIP_MEMORY_SCOPE_AGENT) < target)
      __builtin_amdgcn_s_sleep(8);
  }
  __syncthreads();
  __threadfence();     // acquire: invalidate stale cached lines before halo reads
}

// masks for boundary-corrected stencils: t = 0(row0),1(row1),2(interior),3(H-2),4(H-1)
__device__ inline bool mA5(int t, int e) {
  return (t==0) ? (e<=2) : (t==1) ? (e<=3) : (t==3) ? (e>=1) : (t==4) ? (e>=2) : true;
}
__device__ inline bool mW3(int t, int e) {
  return (t==0) ? (e<=1) : (t==4) ? (e>=1) : true;
}

// ---------------- prep: scalars+barrier, 25x81 stencil table, fp16 weights ---------
__global__ void k_prep(const float* __restrict__ Ka, const float* __restrict__ Kw,
                       const float* __restrict__ miu,
                       const float* __restrict__ W1, const float* __restrict__ b1,
                       const float* __restrict__ W2, const float* __restrict__ W3,
                       float* __restrict__ tab, ushort* __restrict__ w2pk,
                       uint* __restrict__ w1pk, uint* __restrict__ b1pk,
                       ushort* __restrict__ w3fr, float* __restrict__ scal) {
  __shared__ float lka[25], lkw[36], lw1[288], lw3[288];
  int tid = threadIdx.x;   // 1024 threads
  if (tid < 256) scal[tid] = 0.f;   // scalars + barrier counter @192
  if (tid < 25) lka[tid] = Ka[tid];
  if (tid < 36) lkw[tid] = Kw[tid];
  if (tid < 288) { lw1[tid] = W1[tid]; lw3[tid] = W3[tid]; }
  __syncthreads();
  const float mu = miu[0];
  #pragma unroll
  for (int k = 0; k < 2; k++) {
    int idx = tid + k*1024;
    if (idx < 2025) {
      int c = idx / 81, o = idx - c*81;
      int ty = c / 5, tx = c - 5*ty;
      int uy = o / 9 - 4, ux = o % 9 - 4;
      float s = 0.f;
      for (int ey = 0; ey < 5; ey++)
        for (int ex = 0; ex < 5; ex++) {
          int dy = ey + uy, dx = ex + ux;
          if (dy >= 0 && dy < 5 && dx >= 0 && dx < 5 && mA5(ty,ey) && mA5(tx,ex))
            s += lka[ey*5+ex] * lka[dy*5+dx];
        }
      float sw = 0.f;
      for (int ch = 0; ch < 4; ch++)
        for (int ey = 0; ey < 3; ey++)
          for (int ex = 0; ex < 3; ex++) {
            int dy = ey + uy, dx = ex + ux;
            if (dy >= 0 && dy < 3 && dx >= 0 && dx < 3 && mW3(ty,ey) && mW3(tx,ex))
              sw += lkw[ch*9+ey*3+ex] * lkw[ch*9+dy*3+dx];
          }
      tab[idx] = s + mu * sw;
    }
  }
  #pragma unroll
  for (int k = 0; k < 9; k++) {
    int i = tid + k*1024;
    int j = i & 7, l = (i >> 3) & 63, f = i >> 9;
    int t5 = f >> 1, h = f & 1;
    int co = 16*h + (l & 15), ci = 8*(l >> 4) + j;
    w2pk[i] = (ushort)(f2h2(W2[(co*32 + ci)*9 + t5], 0.f) & 0xffffu);
  }
  if (tid < 144) {
    int cp = tid / 9, t = tid % 9;
    w1pk[tid] = f2h2(lw1[(2*cp)*9 + t], lw1[(2*cp+1)*9 + t]);
  }
  if (tid < 16) b1pk[tid] = f2h2(b1[2*tid], b1[2*tid+1]);
  if (tid < 512) {
    int j = tid & 7, l = tid >> 3;
    int tap = l & 15, ch = 8*(l >> 4) + j;
    w3fr[tid] = (tap < 9) ? (ushort)(f2h2(lw3[ch*9 + tap], 0.f) & 0xffffu) : (ushort)0;
  }
}

// ---------------- fused CNN: xk = cnn(x), fp16/MFMA --------------------------------
__launch_bounds__(512)
__global__ void k_cnn(const float* __restrict__ x,
                      const ushort* __restrict__ w2pk, const uint* __restrict__ w1pk,
                      const uint* __restrict__ b1pk, const ushort* __restrict__ w3fr,
                      const float* __restrict__ b2, const float* __restrict__ b3,
                      float* __restrict__ xk) {
  __shared__ __align__(16) uint  h1u[7040];         // 20 x 352
  __shared__ __align__(16) uint  h2u[5472];         // 18 x 304; head doubles as xs
  uint* xs_h2 = h2u;

  const int tid = threadIdx.x;
  const int bimg = blockIdx.z;
  const int oy0 = blockIdx.y * 16, ox0 = blockIdx.x * 16;
  const float* xim = x + (size_t)bimg * IMG;

  for (int i = tid; i < 528; i += 512) {
    int ly = i / 24, lx = i % 24;
    int gy = oy0 + ly - 3, gx = ox0 + lx - 4;
    float v = 0.f;
    if ((unsigned)gy < HH && (unsigned)gx < WW) v = xim[gy*WW + gx];
    xs_h2[i] = f2h2(v, v);
  }
  __syncthreads();

  {
    const int cp = tid & 15;
    const int sg = tid >> 4;
    uint w1r[9];
    #pragma unroll
    for (int k = 0; k < 9; k++) w1r[k] = w1pk[cp*9 + k];
    const uint b1v = b1pk[cp];
    const int kg = cp >> 2, cl = cp & 3;
    #pragma unroll 1
    for (int s = sg; s < 100; s += 32) {
      int row = s / 5, st = s - 5*row;
      int px0 = st * 4;
      uint acc0 = b1v, acc1 = b1v, acc2 = b1v, acc3 = b1v;
      #pragma unroll
      for (int ky = 0; ky < 3; ky++) {
        int base = (row + ky) * 24 + px0;
        uint4 xa = *(const uint4*)&xs_h2[base];
        uint4 xb = *(const uint4*)&xs_h2[base + 4];
        uint xu[8] = {xa.x, xa.y, xa.z, xa.w, xb.x, xb.y, xb.z, xb.w};
        #pragma unroll
        for (int kx = 0; kx < 3; kx++) {
          uint w = w1r[ky*3 + kx];
          acc0 = pkfma(w, xu[1 + kx], acc0);
          acc1 = pkfma(w, xu[2 + kx], acc1);
          acc2 = pkfma(w, xu[3 + kx], acc2);
          acc3 = pkfma(w, xu[4 + kx], acc3);
        }
      }
      int Y = oy0 + row - 2;
      bool rin = (unsigned)Y < HH;
      int ob = row*352 + kg*88 + px0*4 + cl;
      #pragma unroll
      for (int i = 0; i < 4; i++) {
        int X = ox0 + px0 + i - 2;
        uint v = (rin && (unsigned)X < WW) ?
                 pkmax0(i == 0 ? acc0 : (i == 1 ? acc1 : (i == 2 ? acc2 : acc3))) : 0u;
        h1u[ob + i*4] = v;
      }
    }
  }
  __syncthreads();

  const int wv = tid >> 6, lane = tid & 63;
  const int nn = lane & 15, kg = lane >> 4;
  {
    half8 afr[9][2];
    #pragma unroll
    for (int t5 = 0; t5 < 9; t5++) {
      afr[t5][0] = ((const half8*)w2pk)[(t5*2 + 0)*64 + lane];
      afr[t5][1] = ((const half8*)w2pk)[(t5*2 + 1)*64 + lane];
    }
    float b2A[4], b2B[4];
    #pragma unroll
    for (int j = 0; j < 4; j++) { b2A[j] = b2[4*kg + j]; b2B[j] = b2[16 + 4*kg + j]; }

    #pragma unroll 1
    for (int t = wv; t < 27; t += 8) {
      int rp = t / 3, cs = t - 3*rp;
      int tx0 = (cs == 2) ? 10 : (cs << 3);
      int brow = 2*rp + (nn >> 3);
      int bcol = tx0 + (nn & 7);
      f32x4 accA = {0.f,0.f,0.f,0.f}, accB = {0.f,0.f,0.f,0.f};
      #pragma unroll
      for (int ky = 0; ky < 3; ky++)
        #pragma unroll
        for (int kx = 0; kx < 3; kx++) {
          const half8 bfr = *(const half8*)&h1u[(brow+ky)*352 + kg*88 + (bcol+kx)*4];
          accA = __builtin_amdgcn_mfma_f32_16x16x32_f16(afr[ky*3+kx][0], bfr, accA, 0, 0, 0);
          accB = __builtin_amdgcn_mfma_f32_16x16x32_f16(afr[ky*3+kx][1], bfr, accB, 0, 0, 0);
        }
      int gy = oy0 + brow - 1, gx = ox0 + bcol - 1;
      bool inb = ((unsigned)gy < HH) && ((unsigned)gx < WW);
      float v0 = inb ? fmaxf(accA[0] + b2A[0], 0.f) : 0.f;
      float v1 = inb ? fmaxf(accA[1] + b2A[1], 0.f) : 0.f;
      float v2 = inb ? fmaxf(accA[2] + b2A[2], 0.f) : 0.f;
      float v3 = inb ? fmaxf(accA[3] + b2A[3], 0.f) : 0.f;
      uint2 uA = make_uint2(f2h2(v0, v1), f2h2(v2, v3));
      v0 = inb ? fmaxf(accB[0] + b2B[0], 0.f) : 0.f;
      v1 = inb ? fmaxf(accB[1] + b2B[1], 0.f) : 0.f;
      v2 = inb ? fmaxf(accB[2] + b2B[2], 0.f) : 0.f;
      v3 = inb ? fmaxf(accB[3] + b2B[3], 0.f) : 0.f;
      uint2 uB = make_uint2(f2h2(v0, v1), f2h2(v2, v3));
      int base = brow*304 + bcol*4 + (kg & 1)*2;
      *(uint2*)&h2u[base + (kg >> 1)*76]       = uA;
      *(uint2*)&h2u[base + (2 + (kg >> 1))*76] = uB;
    }
  }
  __syncthreads();

  float* Tlds = (float*)h1u;
  {
    const half8 w3f = ((const half8*)w3fr)[lane];
    const int tap = nn;
    #pragma unroll 1
    for (int t = wv; t < 27; t += 8) {
      int rp = t / 3, cs = t - 3*rp;
      int tx0 = (cs == 2) ? 10 : (cs << 3);
      int ay = 2*rp + (nn >> 3);
      int ax = tx0 + (nn & 7);
      const half8 afrag = *(const half8*)&h2u[ay*304 + kg*76 + ax*4];
      f32x4 z = {0.f,0.f,0.f,0.f};
      f32x4 T4 = __builtin_amdgcn_mfma_f32_16x16x32_f16(afrag, w3f, z, 0, 0, 0);
      if (tap < 9) {
        int ty = 2*rp + (kg >> 1);
        int txb = tx0 + 4*(kg & 1);
        float* dst = &Tlds[ty*180 + tap*20 + txb];
        if (cs == 2) {
          dst[0] = T4[0]; dst[1] = T4[1]; dst[2] = T4[2]; dst[3] = T4[3];
        } else {
          *(f32x4*)dst = T4;
        }
      }
    }
  }
  __syncthreads();

  {
    const int half = tid & 1, px = tid >> 1;
    const int oy = px >> 4, ox = px & 15;
    float s = 0.f;
    if (half == 0) {
      #pragma unroll
      for (int t = 0; t < 4; t++)
        s += Tlds[(oy + t/3)*180 + t*20 + (ox + t%3)];
    } else {
      #pragma unroll
      for (int t = 4; t < 9; t++)
        s += Tlds[(oy + t/3)*180 + t*20 + (ox + t%3)];
    }
    float other = __shfl_xor(s, 1, 64);
    if (half == 0) {
      float tot = s + other + b3[0] + xim[(size_t)(oy0+oy)*WW + ox0 + ox];
      xk[(size_t)bimg*IMG + (size_t)(oy0+oy)*WW + ox0 + ox] = tot;
    }
  }
}

// ---------------- M-apply (32x64 tiles; used by k_M0 and fallback kernels) ---------
__device__ __forceinline__ void apply_M2(const float (*ssrc)[76], float* bandv,
    const float* Gs, const float* __restrict__ tab,
    int tid, int oy0, int ox0, float* accv) {
  const int sy = tid >> 3, sx0 = (tid & 7) * 8;
  #pragma unroll
  for (int k = 0; k < 8; k++) accv[k] = 0.f;
  #pragma unroll 1
  for (int oyy = 0; oyy < 9; oyy++) {
    float g[9];
    #pragma unroll
    for (int t = 0; t < 9; t++) g[t] = Gs[oyy*9+t];
    const float* row = &ssrc[sy+oyy][sx0];
    float4 r0 = *(const float4*)(row);
    float4 r1 = *(const float4*)(row+4);
    float4 r2 = *(const float4*)(row+8);
    float4 r3 = *(const float4*)(row+12);
    float v[16] = {r0.x,r0.y,r0.z,r0.w, r1.x,r1.y,r1.z,r1.w,
                   r2.x,r2.y,r2.z,r2.w, r3.x,r3.y,r3.z,r3.w};
    #pragma unroll
    for (int k = 0; k < 8; k++) {
      float a = accv[k];
      #pragma unroll
      for (int t = 0; t < 9; t++) a = fmaf(g[t], v[k+t], a);
      accv[k] = a;
    }
  }
  const int by = blockIdx.y, bx = blockIdx.x;
  const bool eT = (by == 0), eB = (by == (int)gridDim.y - 1);
  const bool eL = (bx == 0), eR = (bx == (int)gridDim.x - 1);
  if (eT | eB | eL | eR) {
    const int nTop = eT ? 128 : 0;
    const int nBot = eB ? 128 : 0;
    const int yl = eT ? 2 : 0, yh = eB ? 30 : 32;
    const int nL = eL ? 2*(yh-yl) : 0;
    const int nR = eR ? 2*(yh-yl) : 0;
    const int nBand = nTop + nBot + nL + nR;
    if (tid < nBand) {
      int i = tid, bsy, bsx;
      if (i < nTop) { bsy = i >> 6; bsx = i & 63; }
      else if (i < nTop + nBot) { i -= nTop; bsy = 30 + (i >> 6); bsx = i & 63; }
      else if (i < nTop + nBot + nL) { i -= nTop + nBot; bsy = yl + (i >> 1); bsx = i & 1; }
      else { i -= nTop + nBot + nL; bsy = yl + (i >> 1); bsx = 62 + (i & 1); }
      const int gy = oy0 + bsy, gx = ox0 + bsx;
      int ty = (gy == 0) ? 0 : (gy == 1) ? 1 : (gy == HH-1) ? 4 : (gy == HH-2) ? 3 : 2;
      int tx = (gx == 0) ? 0 : (gx == 1) ? 1 : (gx == WW-1) ? 4 : (gx == WW-2) ? 3 : 2;
      const float* S = tab + (ty*5 + tx)*81;
      float a = 0.f;
      #pragma unroll
      for (int oy = 0; oy < 9; oy++) {
        const float* r = &ssrc[bsy+oy][bsx];
        #pragma unroll
        for (int ox = 0; ox < 9; ox++) a = fmaf(S[oy*9+ox], r[ox], a);
      }
      bandv[tid] = a;
    }
    __syncthreads();
    #pragma unroll
    for (int k = 0; k < 8; k++) {
      const int sx = sx0 + k;
      const int gy = oy0 + sy, gx = ox0 + sx;
      if ((gy < 2) || (gy >= HH-2) || (gx < 2) || (gx >= WW-2)) {
        int idx;
        if (eT && sy < 2) idx = sy*64 + sx;
        else if (eB && sy >= 30) idx = nTop + (sy-30)*64 + sx;
        else if (eL && sx < 2) idx = nTop + nBot + (sy-yl)*2 + sx;
        else idx = nTop + nBot + nL + (sy-yl)*2 + (sx-62);
        accv[k] = bandv[idx];
      }
    }
  }
}

// ---------------- k_M0: fused rhs + r = M(xk) - rhs, p = -r, rtr reduction ---------
__launch_bounds__(256)
__global__ void k_M0(const float* __restrict__ xk, const float* __restrict__ sino,
                     const float* __restrict__ x,
                     float* __restrict__ outR, float* __restrict__ outP,
                     const float* __restrict__ tab,
                     const float* __restrict__ Ka, const float* __restrict__ Kw,
                     const float* __restrict__ laam, const float* __restrict__ miu,
                     float* __restrict__ rtrOut) {
  __shared__ __align__(16) float ssrc[40][76];
  __shared__ __align__(16) float tbuf[36][68];
  __shared__ __align__(16) float ssin[36][68];
  __shared__ __align__(16) float sx[36][68];
  __shared__ float Gs[81], kas[25], kws[36];
  __shared__ float red[4];
  const int tid = threadIdx.x;
  const int bimg = blockIdx.z;
  const int oy0 = blockIdx.y*32, ox0 = blockIdx.x*64;
  if (tid < 81) Gs[tid] = tab[972 + tid];
  if (tid >= 81 && tid < 106) kas[tid-81] = Ka[tid-81];
  if (tid >= 106 && tid < 142) kws[tid-106] = Kw[tid-106];
  const float mu = miu[0];
  const float lam = laam[0];
  const float* sxk = xk + (size_t)bimg*IMG;
  const float* ssi = sino + (size_t)bimg*IMG;
  const float* sxi = x + (size_t)bimg*IMG;

  for (int i = tid; i < 40*76; i += 256) {
    int ly = i/76, lx = i%76;
    int gy = oy0 + ly - 4, gx = ox0 + lx - 4;
    bool in = (lx < 72) && (gy >= 0 && gy < HH && gx >= 0 && gx < WW);
    ssrc[ly][lx] = in ? sxk[gy*WW+gx] : 0.f;
  }
  for (int i = tid; i < 36*68; i += 256) {
    int ly = i/68, lx = i%68;
    int gy = oy0 + ly - 2, gx = ox0 + lx - 2;
    bool in = (gy >= 0 && gy < HH && gx >= 0 && gx < WW);
    ssin[ly][lx] = in ? ssi[gy*WW+gx] : 0.f;
    sx[ly][lx]   = in ? sxi[gy*WW+gx] : 0.f;
  }
  __syncthreads();

  float accv[8];
  apply_M2(ssrc, &tbuf[0][0], Gs, tab, tid, oy0, ox0, accv);

  const int sy = tid >> 3, sx0 = (tid & 7) * 8;
  float rhsv[8];
  #pragma unroll
  for (int k = 0; k < 8; k++) rhsv[k] = 0.f;
  {
    #pragma unroll
    for (int dy = 0; dy < 5; dy++) {
      const float* row = &ssin[sy+4-dy][sx0];
      float4 r0 = *(const float4*)(row);
      float4 r1 = *(const float4*)(row+4);
      float4 r2 = *(const float4*)(row+8);
      float w[12] = {r0.x,r0.y,r0.z,r0.w, r1.x,r1.y,r1.z,r1.w, r2.x,r2.y,r2.z,r2.w};
      #pragma unroll
      for (int k = 0; k < 8; k++)
        #pragma unroll
        for (int dx = 0; dx < 5; dx++)
          rhsv[k] = fmaf(kas[dy*5+dx], w[k+4-dx], rhsv[k]);
    }
  }
  #pragma unroll 1
  for (int ch = 0; ch < 4; ch++) {
    __syncthreads();
    {
      float kw[9];
      #pragma unroll
      for (int k = 0; k < 9; k++) kw[k] = kws[ch*9 + k];
      #pragma unroll 1
      for (int item = tid; item < 2244; item += 256) {
        int dy = item / 66, dx = item - 66*dy;
        int gy = oy0 + dy - 1, gx = ox0 + dx - 1;
        float v = 0.f;
        if (gy >= 0 && gy < HH && gx >= 0 && gx < WW) {
          float wu = 0.f;
          #pragma unroll
          for (int e = 0; e < 9; e++) wu = fmaf(kw[e], sx[dy + e/3][dx + e%3], wu);
          v = fmaxf(wu - lam, 0.f) - fmaxf(-wu - lam, 0.f);
        }
        tbuf[dy][dx] = v;
      }
    }
    __syncthreads();
    {
      float kw[9];
      #pragma unroll
      for (int k = 0; k < 9; k++) kw[k] = mu * kws[ch*9 + k];
      #pragma unroll
      for (int dy = 0; dy < 3; dy++) {
        const float* row = &tbuf[sy+2-dy][sx0];
        float4 r0 = *(const float4*)(row);
        float4 r1 = *(const float4*)(row+4);
        float4 r2 = *(const float4*)(row+8);
        float w[12] = {r0.x,r0.y,r0.z,r0.w, r1.x,r1.y,r1.z,r1.w, r2.x,r2.y,r2.z,r2.w};
        #pragma unroll
        for (int k = 0; k < 8; k++)
          #pragma unroll
          for (int dx = 0; dx < 3; dx++)
            rhsv[k] = fmaf(kw[dy*3+dx], w[k+2-dx], rhsv[k]);
      }
    }
  }

  const int gy = oy0 + sy, gx0 = ox0 + sx0;
  float part = 0.f;
  #pragma unroll
  for (int k = 0; k < 8; k++) {
    size_t idx = (size_t)bimg*IMG + gy*WW + gx0 + k;
    float rv = accv[k] - rhsv[k];
    outR[idx] = rv;
    outP[idx] = -rv;
    part += rv*rv;
  }
  atomic_block_sum(part, red, &rtrOut[bimg]);
}

// ---------------- persistent CG: 512 blocks (8x,8y,8img), 64x64 tile, 16px/thread --
__device__ inline void stage_frame64(float (*ssrc)[76], const float* __restrict__ src,
                                     size_t ib, int oy0, int ox0, int tid) {
  for (int i = tid; i < 1376; i += 256) {
    int ly, lx;
    if (i < 304) { ly = i/76; lx = i - 76*ly; }
    else if (i < 608) { int j = i-304; int q = j/76; ly = 68 + q; lx = j - 76*q; }
    else { int j = i-608; int q = j/12; ly = 4 + q; int c = j - 12*q; lx = (c < 4) ? c : 64 + c; }
    int gy = oy0 + ly - 4, gx = ox0 + lx - 4;
    float v = 0.f;
    if (lx < 72 && (unsigned)gy < HH && (unsigned)gx < WW)
      v = src[ib + (size_t)gy*WW + gx];
    ssrc[ly][lx] = v;
  }
}

__device__ inline void apply_cg(const float (*ssrc)[76], float* bandv,
    const float* Gs, const float* __restrict__ tab,
    int tid, int oy0, int ox0, int by, int bx, float (*q16)[8]) {
  const int sy = tid >> 3, sx0 = (tid & 7) * 8;
  #pragma unroll
  for (int s = 0; s < 2; s++) {
    #pragma unroll
    for (int k = 0; k < 8; k++) q16[s][k] = 0.f;
    const int R = sy + 32*s;
    #pragma unroll 1
    for (int oyy = 0; oyy < 9; oyy++) {
      float g[9];
      #pragma unroll
      for (int t = 0; t < 9; t++) g[t] = Gs[oyy*9+t];
      const float* row = &ssrc[R+oyy][sx0];
      float4 r0 = *(const float4*)(row);
      float4 r1 = *(const float4*)(row+4);
      float4 r2 = *(const float4*)(row+8);
      float4 r3 = *(const float4*)(row+12);
      float v[16] = {r0.x,r0.y,r0.z,r0.w, r1.x,r1.y,r1.z,r1.w,
                     r2.x,r2.y,r2.z,r2.w, r3.x,r3.y,r3.z,r3.w};
      #pragma unroll
      for (int k = 0; k < 8; k++) {
        float a = q16[s][k];
        #pragma unroll
        for (int t = 0; t < 9; t++) a = fmaf(g[t], v[k+t], a);
        q16[s][k] = a;
      }
    }
  }
  const bool eT = (by == 0), eB = (by == 7);
  const bool eL = (bx == 0), eR = (bx == 7);
  if (eT | eB | eL | eR) {
    const int nTop = eT ? 128 : 0;
    const int nBot = eB ? 128 : 0;
    const int yl = eT ? 2 : 0, yh = eB ? 62 : 64;
    const int nL = eL ? 2*(yh-yl) : 0;
    const int nR = eR ? 2*(yh-yl) : 0;
    const int nBand = nTop + nBot + nL + nR;
    if (tid < nBand) {
      int i = tid, bsy, bsx;
      if (i < nTop) { bsy = i >> 6; bsx = i & 63; }
      else if (i < nTop + nBot) { i -= nTop; bsy = 62 + (i >> 6); bsx = i & 63; }
      else if (i < nTop + nBot + nL) { i -= nTop + nBot; bsy = yl + (i >> 1); bsx = i & 1; }
      else { i -= nTop + nBot + nL; bsy = yl + (i >> 1); bsx = 62 + (i & 1); }
      const int gy = oy0 + bsy, gx = ox0 + bsx;
      int ty = (gy == 0) ? 0 : (gy == 1) ? 1 : (gy == HH-1) ? 4 : (gy == HH-2) ? 3 : 2;
      int tx = (gx == 0) ? 0 : (gx == 1) ? 1 : (gx == WW-1) ? 4 : (gx == WW-2) ? 3 : 2;
      const float* S = tab + (ty*5 + tx)*81;
      float a = 0.f;
      #pragma unroll
      for (int oy = 0; oy < 9; oy++) {
        const float* r = &ssrc[bsy+oy][bsx];
        #pragma unroll
        for (int ox = 0; ox < 9; ox++) a = fmaf(S[oy*9+ox], r[ox], a);
      }
      bandv[tid] = a;
    }
    __syncthreads();
    #pragma unroll
    for (int s = 0; s < 2; s++) {
      const int R = sy + 32*s;
      const int gy = oy0 + R;
      #pragma unroll
      for (int k = 0; k < 8; k++) {
        const int sx = sx0 + k;
        const int gx = ox0 + sx;
        if ((gy < 2) || (gy >= HH-2) || (gx < 2) || (gx >= WW-2)) {
          int idx;
          if (eT && R < 2) idx = R*64 + sx;
          else if (eB && R >= 62) idx = nTop + (R-62)*64 + sx;
          else if (eL && sx < 2) idx = nTop + nBot + (R-yl)*2 + sx;
          else idx = nTop + nBot + nL + (R-yl)*2 + (sx-62);
          q16[s][k] = bandv[idx];
        }
      }
    }
  }
}

__launch_bounds__(256, 2)
__global__ void k_cg(const float* __restrict__ xk0, const float* __restrict__ rA,
                     const float* __restrict__ pA, float* __restrict__ pg,
                     const float* __restrict__ tab, float* __restrict__ scal,
                     uint* __restrict__ bar, float* __restrict__ dout) {
  __shared__ __align__(16) float ssrc[72][76];
  __shared__ float bandv[256];
  __shared__ float Gs[81];
  __shared__ float red[12];
  const int tid = threadIdx.x;
  const int bx = blockIdx.x, by = blockIdx.y, bimg = blockIdx.z;
  const int oy0 = by*64, ox0 = bx*64;
  if (tid < 81) Gs[tid] = tab[972 + tid];
  const size_t ib = (size_t)bimg*IMG;
  const int sy = tid >> 3, sx0v = (tid & 7)*8;
  const size_t base0 = ib + (size_t)(oy0+sy)*WW + ox0 + sx0v;
  const size_t base1 = base0 + (size_t)32*WW;
  uint nb = 0;

  float xk16[2][8], r16[2][8], p16[2][8], q16[2][8];
  {
    float4 a0 = *(const float4*)&xk0[base0];
    float4 a1 = *(const float4*)&xk0[base0+4];
    float4 a2 = *(const float4*)&xk0[base1];
    float4 a3 = *(const float4*)&xk0[base1+4];
    xk16[0][0]=a0.x; xk16[0][1]=a0.y; xk16[0][2]=a0.z; xk16[0][3]=a0.w;
    xk16[0][4]=a1.x; xk16[0][5]=a1.y; xk16[0][6]=a1.z; xk16[0][7]=a1.w;
    xk16[1][0]=a2.x; xk16[1][1]=a2.y; xk16[1][2]=a2.z; xk16[1][3]=a2.w;
    xk16[1][4]=a3.x; xk16[1][5]=a3.y; xk16[1][6]=a3.z; xk16[1][7]=a3.w;
    float4 b0 = *(const float4*)&rA[base0];
    float4 b1 = *(const float4*)&rA[base0+4];
    float4 b2 = *(const float4*)&rA[base1];
    float4 b3 = *(const float4*)&rA[base1+4];
    r16[0][0]=b0.x; r16[0][1]=b0.y; r16[0][2]=b0.z; r16[0][3]=b0.w;
    r16[0][4]=b1.x; r16[0][5]=b1.y; r16[0][6]=b1.z; r16[0][7]=b1.w;
    r16[1][0]=b2.x; r16[1][1]=b2.y; r16[1][2]=b2.z; r16[1][3]=b2.w;
    r16[1][4]=b3.x; r16[1][5]=b3.y; r16[1][6]=b3.z; r16[1][7]=b3.w;
    #pragma unroll
    for (int s = 0; s < 2; s++)
      #pragma unroll
      for (int k = 0; k < 8; k++) p16[s][k] = -r16[s][k];
  }

  // ---- q0 = M(p0): frame from pA, interior from regs ----
  stage_frame64(ssrc, pA, ib, oy0, ox0, tid);
  #pragma unroll
  for (int s = 0; s < 2; s++)
    #pragma unroll
    for (int k = 0; k < 8; k++) ssrc[sy + 32*s + 4][sx0v + 4 + k] = p16[s][k];
  __syncthreads();
  apply_cg(ssrc, bandv, Gs, tab, tid, oy0, ox0, by, bx, q16);
  {
    float sd = 0.f, sq = 0.f;
    #pragma unroll
    for (int s = 0; s < 2; s++)
      #pragma unroll
      for (int k = 0; k < 8; k++) { sd += p16[s][k]*q16[s][k]; sq += q16[s][k]*q16[s][k]; }
    reduce3_atomic(sd, sq, 0.f, red, &scal[bimg], &scal[96+bimg], nullptr);
  }
  gbar(bar, (++nb)*512u);
  float den_p = __hip_atomic_load(&scal[bimg],     __ATOMIC_RELAXED, __HIP_MEMORY_SCOPE_AGENT);
  float qq_p  = __hip_atomic_load(&scal[96+bimg],  __ATOMIC_RELAXED, __HIP_MEMORY_SCOPE_AGENT);
  float rtr_p = __hip_atomic_load(&scal[144+bimg], __ATOMIC_RELAXED, __HIP_MEMORY_SCOPE_AGENT);
  float rq_p  = -den_p;

  #pragma unroll 1
  for (int it = 1; it <= 5; ++it) {
    const float al = rtr_p / den_p;
    const float rtr_c = fmaf(al, fmaf(al, qq_p, 2.f*rq_p), rtr_p);
    const float be = rtr_c / rtr_p;
    #pragma unroll
    for (int s = 0; s < 2; s++)
      #pragma unroll
      for (int k = 0; k < 8; k++) {
        xk16[s][k] = fmaf(al, p16[s][k], xk16[s][k]);
        r16[s][k]  = fmaf(al, q16[s][k], r16[s][k]);
        p16[s][k]  = fmaf(be, p16[s][k], -r16[s][k]);
      }
    *(float4*)&pg[base0]   = make_float4(p16[0][0], p16[0][1], p16[0][2], p16[0][3]);
    *(float4*)&pg[base0+4] = make_float4(p16[0][4], p16[0][5], p16[0][6], p16[0][7]);
    *(float4*)&pg[base1]   = make_float4(p16[1][0], p16[1][1], p16[1][2], p16[1][3]);
    *(float4*)&pg[base1+4] = make_float4(p16[1][4], p16[1][5], p16[1][6], p16[1][7]);
    gbar(bar, (++nb)*512u);
    stage_frame64(ssrc, pg, ib, oy0, ox0, tid);
    #pragma unroll
    for (int s = 0; s < 2; s++)
      #pragma unroll
      for (int k = 0; k < 8; k++) ssrc[sy + 32*s + 4][sx0v + 4 + k] = p16[s][k];
    __syncthreads();
    apply_cg(ssrc, bandv, Gs, tab, tid, oy0, ox0, by, bx, q16);
    {
      float sd = 0.f, sr = 0.f, sq = 0.f;
      #pragma unroll
      for (int s = 0; s < 2; s++)
        #pragma unroll
        for (int k = 0; k < 8; k++) {
          sd += p16[s][k]*q16[s][k];
          sr += r16[s][k]*q16[s][k];
          sq += q16[s][k]*q16[s][k];
        }
      reduce3_atomic(sd, sr, sq, red, &scal[it*8+bimg], &scal[48+it*8+bimg],
                     &scal[96+it*8+bimg]);
    }
    gbar(bar, (++nb)*512u);
    den_p = __hip_atomic_load(&scal[it*8+bimg],    __ATOMIC_RELAXED, __HIP_MEMORY_SCOPE_AGENT);
    rq_p  = __hip_atomic_load(&scal[48+it*8+bimg], __ATOMIC_RELAXED, __HIP_MEMORY_SCOPE_AGENT);
    qq_p  = __hip_atomic_load(&scal[96+it*8+bimg], __ATOMIC_RELAXED, __HIP_MEMORY_SCOPE_AGENT);
    rtr_p = rtr_c;
  }

  {
    const float al = rtr_p / den_p;
    *(float4*)&dout[base0] = make_float4(
      fmaf(al,p16[0][0],xk16[0][0]), fmaf(al,p16[0][1],xk16[0][1]),
      fmaf(al,p16[0][2],xk16[0][2]), fmaf(al,p16[0][3],xk16[0][3]));
    *(float4*)&dout[base0+4] = make_float4(
      fmaf(al,p16[0][4],xk16[0][4]), fmaf(al,p16[0][5],xk16[0][5]),
      fmaf(al,p16[0][6],xk16[0][6]), fmaf(al,p16[0][7],xk16[0][7]));
    *(float4*)&dout[base1] = make_float4(
      fmaf(al,p16[1][0],xk16[1][0]), fmaf(al,p16[1][1],xk16[1][1]),
      fmaf(al,p16[1][2],xk16[1][2]), fmaf(al,p16[1][3],xk16[1][3]));
    *(float4*)&dout[base1+4] = make_float4(
      fmaf(al,p16[1][4],xk16[1][4]), fmaf(al,p16[1][5],xk16[1][5]),
      fmaf(al,p16[1][6],xk16[1][6]), fmaf(al,p16[1][7],xk16[1][7]));
  }
}

// ---------------- fallback kernels (proven round-9 path) ---------------------------
template<int MODE>
__launch_bounds__(256)
__global__ void k_M(const float* __restrict__ srcA, const float* __restrict__ srcB,
                    float* __restrict__ outQ, float* __restrict__ outP,
                    const float* __restrict__ tab,
                    const float* __restrict__ beN, const float* __restrict__ beD,
                    float* __restrict__ acc, float* __restrict__ rqOut,
                    float* __restrict__ qqOut) {
  __shared__ __align__(16) float ssrc[40][76];
  __shared__ float bandv[256];
  __shared__ float Gs[81];
  __shared__ float red[12];
  const int tid = threadIdx.x;
  const int bimg = blockIdx.z;
  const int oy0 = blockIdx.y*32, ox0 = blockIdx.x*64;
  if (tid < 81) Gs[tid] = tab[972 + tid];
  float be = 0.f;
  if (MODE == 2) be = beN[bimg] / beD[bimg];
  const float* sA = srcA + (size_t)bimg*IMG;
  const float* sB = (MODE == 2) ? srcB + (size_t)bimg*IMG : nullptr;

  for (int i = tid; i < 40*76; i += 256) {
    int ly = i/76, lx = i%76;
    int gy = oy0 + ly - 4, gx = ox0 + lx - 4;
    bool in = (lx < 72) && (gy >= 0 && gy < HH && gx >= 0 && gx < WW);
    float v = 0.f;
    if (MODE == 2) {
      if (in) {
        v = -sA[gy*WW+gx] + be * sB[gy*WW+gx];
        if (ly >= 4 && ly < 36 && lx >= 4 && lx < 68)
          outP[(size_t)bimg*IMG + gy*WW + gx] = v;
      }
    } else {
      if (in) v = sA[gy*WW+gx];
    }
    ssrc[ly][lx] = v;
  }
  __syncthreads();

  float accv[8];
  apply_M2(ssrc, bandv, Gs, tab, tid, oy0, ox0, accv);

  const int sy = tid >> 3, sx0 = (tid & 7) * 8;
  const int gy = oy0 + sy, gx0 = ox0 + sx0;
  if (MODE == 1) {
    float pq = 0.f, qq = 0.f;
    #pragma unroll
    for (int k = 0; k < 8; k++) {
      size_t idx = (size_t)bimg*IMG + gy*WW + gx0 + k;
      float pv = ssrc[sy+4][sx0+4+k];
      float qv = accv[k];
      outQ[idx] = qv;
      pq += pv * qv;
      qq += qv * qv;
    }
    reduce3_atomic(pq, -pq, qq, red, &acc[bimg], rqOut ? &rqOut[bimg] : nullptr,
                   qqOut ? &qqOut[bimg] : nullptr);
  } else {
    float part = 0.f;
    #pragma unroll
    for (int k = 0; k < 8; k++) {
      size_t idx = (size_t)bimg*IMG + gy*WW + gx0 + k;
      float pv = ssrc[sy+4][sx0+4+k];
      outQ[idx] = accv[k];
      part += pv * accv[k];
    }
    atomic_block_sum(part, red, &acc[bimg]);
  }
}

__launch_bounds__(256)
__global__ void k_it(float* __restrict__ xk,
                     const float* __restrict__ rold, float* __restrict__ rnew,
                     const float* __restrict__ pold, float* __restrict__ pnew,
                     const float* __restrict__ qold, float* __restrict__ qnew,
                     const float* __restrict__ tab,
                     float* __restrict__ scal, int it, int storeQ) {
  __shared__ __align__(16) float ssrc[40][76];
  __shared__ float rlds[2048];
  __shared__ float bandv[256];
  __shared__ float Gs[81];
  __shared__ float red[12];
  const int tid = threadIdx.x;
  const int bimg = blockIdx.z;
  const int oy0 = blockIdx.y*32, ox0 = blockIdx.x*64;
  if (tid < 81) Gs[tid] = tab[972 + tid];
  const float den_p = scal[       (it-1)*8 + bimg];
  const float rq_p  = scal[ 48 + (it-1)*8 + bimg];
  const float qq_p  = scal[ 96 + (it-1)*8 + bimg];
  const float rtr_p = scal[144 + (it-1)*8 + bimg];
  const float al = rtr_p / den_p;
  const float rtr_c = fmaf(al, fmaf(al, qq_p, 2.f*rq_p), rtr_p);
  const float be = rtr_c / rtr_p;
  if (tid == 0) scal[144 + it*8 + bimg] = rtr_c;
  const size_t ib = (size_t)bimg*IMG;

  for (int i = tid; i < 40*76; i += 256) {
    int ly = i/76, lx = i%76;
    int gy = oy0 + ly - 4, gx = ox0 + lx - 4;
    bool in = (lx < 72) && (gy >= 0 && gy < HH && gx >= 0 && gx < WW);
    float v = 0.f;
    if (in) {
      size_t g = ib + (size_t)gy*WW + gx;
      float pgv = pold[g];
      float rn = fmaf(al, qold[g], rold[g]);
      v = fmaf(be, pgv, -rn);
      if (ly >= 4 && ly < 36 && lx >= 4 && lx < 68) {
        pnew[g] = v;
        rnew[g] = rn;
        xk[g] = fmaf(al, pgv, xk[g]);
        rlds[(ly-4)*64 + (lx-4)] = rn;
      }
    }
    ssrc[ly][lx] = v;
  }
  __syncthreads();

  float accv[8];
  apply_M2(ssrc, bandv, Gs, tab, tid, oy0, ox0, accv);

  const int sy = tid >> 3, sx0 = (tid & 7) * 8;
  const int gy = oy0 + sy, gx0 = ox0 + sx0;
  float s_den = 0.f, s_rq = 0.f, s_qq = 0.f;
  #pragma unroll
  for (int k = 0; k < 8; k++) {
    size_t idx = ib + (size_t)gy*WW + gx0 + k;
    float qv = accv[k];
    float pv = ssrc[sy+4][sx0+4+k];
    float rv = rlds[sy*64 + sx0 + k];
    if (storeQ) qnew[idx] = qv;
    s_den += pv*qv;
    s_rq  += rv*qv;
    s_qq  += qv*qv;
  }
  reduce3_atomic(s_den, s_rq, s_qq, red, &scal[it*8+bimg], &scal[48+it*8+bimg],
                 &scal[96+it*8+bimg]);
}

__launch_bounds__(256)
__global__ void k_final(const float* __restrict__ xk, const float* __restrict__ p,
                        const float* __restrict__ num, const float* __restrict__ den,
                        float* __restrict__ out) {
  const int tid = threadIdx.x;
  const int bimg = blockIdx.x >> 8;
  const size_t idx4 = (size_t)blockIdx.x * 256 + tid;
  const float al = num[bimg] / den[bimg];
  float4 xv = ((const float4*)xk)[idx4];
  float4 pv = ((const float4*)p)[idx4];
  float4 o;
  o.x = xv.x + al*pv.x; o.y = xv.y + al*pv.y; o.z = xv.z + al*pv.z; o.w = xv.w + al*pv.w;
  ((float4*)out)[idx4] = o;
}

extern "C" void kernel_launch(void* const* d_in, const int* in_sizes, int n_in,
                              void* d_out, int out_size, void* d_ws, size_t ws_size,
                              hipStream_t stream) {
  const float* sino = (const float*)d_in[0];
  const float* x    = (const float*)d_in[1];
  const float* laam = (const float*)d_in[2];
  const float* miu  = (const float*)d_in[3];
  const float* Kw   = (const float*)d_in[4];
  const float* Ka   = (const float*)d_in[5];
  const float* W1   = (const float*)d_in[6];
  const float* b1   = (const float*)d_in[7];
  const float* W2   = (const float*)d_in[8];
  const float* b2   = (const float*)d_in[9];
  const float* W3   = (const float*)d_in[10];
  const float* b3   = (const float*)d_in[11];

  float* ws = (float*)d_ws;
  float* tail = ws + (size_t)6*NTOT;
  float* tab  = tail;                   // 2048
  float* scal = tail + 2048;            // 256 floats (scalars + barrier @192)
  uint*  bar  = (uint*)(scal + 192);
  ushort* w2pk = (ushort*)(scal + 256);
  uint*   w1pk = (uint*)(w2pk + 9216);
  uint*   b1pk = w1pk + 144;
  ushort* w3fr = (ushort*)(b1pk + 16);
  float* dout = (float*)d_out;

  // residency check for the persistent kernel (pure query, deterministic)
  int nbOcc = 0;
  (void)hipOccupancyMaxActiveBlocksPerMultiprocessor(&nbOcc, k_cg, 256, 0);
  const bool persistent = (nbOcc >= 2);

  k_prep<<<1, 1024, 0, stream>>>(Ka, Kw, miu, W1, b1, W2, W3, tab, w2pk, w1pk,
                                 b1pk, w3fr, scal);

  float* xk = ws;
  k_cnn<<<dim3(32,32,8), 512, 0, stream>>>(x, w2pk, w1pk, b1pk, w3fr, b2, b3, xk);

  dim3 mg(8,16,8);
  float* rA = ws + (size_t)NTOT;
  float* pA = ws + 2*(size_t)NTOT;
  float* pg = ws + 3*(size_t)NTOT;
  k_M0<<<mg,256,0,stream>>>(xk, sino, x, rA, pA, tab, Ka, Kw, laam, miu, &scal[144]);

  if (persistent) {
    k_cg<<<dim3(8,8,8), 256, 0, stream>>>(xk, rA, pA, pg, tab, scal, bar, dout);
  } else {
    float* pB = ws + 4*(size_t)NTOT;
    float* qB = ws + 5*(size_t)NTOT;
    float* qA = dout;
    k_M<1><<<mg,256,0,stream>>>(pA, nullptr, qA, nullptr, tab,
                                nullptr, nullptr, &scal[0], &scal[48], &scal[96]);
    float *rc=rA, *rn=pg, *pc=pA, *pn=pB, *qc=qA, *qn=qB;
    for (int it = 1; it <= 5; it++) {
      k_it<<<mg,256,0,stream>>>(xk, rc, rn, pc, pn, qc, qn, tab, scal,
                                it, it < 5 ? 1 : 0);
      float* t;
      t = rc; rc = rn; rn = t;
      t = pc; pc = pn; pn = t;
      t = qc; qc = qn; qn = t;
    }
    k_final<<<2048,256,0,stream>>>(xk, pc, &scal[144+40], &scal[40], dout);
  }
}

// Round 13
// 388.730 us; speedup vs baseline: 1.0021x; 1.0021x over previous
//
#include <hip/hip_runtime.h>

#define HH 512
#define WW 512
#define BB 8
#define IMG (HH*WW)
#define NTOT (BB*IMG)

typedef float f32x4 __attribute__((ext_vector_type(4)));
typedef _Float16 half8 __attribute__((ext_vector_type(8)));

__device__ inline uint f2h2(float a, float b) {
  uint d; asm("v_cvt_pkrtz_f16_f32 %0, %1, %2" : "=v"(d) : "v"(a), "v"(b)); return d;
}
__device__ inline uint pkfma(uint a, uint b, uint c) {
  uint d; asm("v_pk_fma_f16 %0, %1, %2, %3" : "=v"(d) : "v"(a), "v"(b), "v"(c)); return d;
}
__device__ inline uint pkmax0(uint a) {
  uint d, z = 0u; asm("v_pk_max_f16 %0, %1, %2" : "=v"(d) : "v"(a), "v"(z)); return d;
}

__device__ inline void atomic_block_sum(float part, float* red, float* dst) {
  for (int off = 32; off > 0; off >>= 1) part += __shfl_down(part, off, 64);
  int lane = threadIdx.x & 63, w = threadIdx.x >> 6;
  if (lane == 0) red[w] = part;
  __syncthreads();
  if (threadIdx.x == 0) atomicAdd(dst, red[0] + red[1] + red[2] + red[3]);
}

__device__ inline void reduce3_atomic(float a, float b, float c, float* red,
                                      float* da, float* db, float* dc) {
  for (int off = 32; off > 0; off >>= 1) {
    a += __shfl_down(a, off, 64);
    b += __shfl_down(b, off, 64);
    c += __shfl_down(c, off, 64);
  }
  int lane = threadIdx.x & 63, w = threadIdx.x >> 6;
  if (lane == 0) { red[w*3] = a; red[w*3+1] = b; red[w*3+2] = c; }
  __syncthreads();
  if (threadIdx.x == 0) {
    atomicAdd(da, red[0]+red[3]+red[6]+red[9]);
    if (db) atomicAdd(db, red[1]+red[4]+red[7]+red[10]);
    if (dc) atomicAdd(dc, red[2]+red[5]+red[8]+red[11]);
  }
}

// masks for boundary-corrected stencils: t = 0(row0),1(row1),2(interior),3(H-2),4(H-1)
__device__ inline bool mA5(int t, int e) {
  return (t==0) ? (e<=2) : (t==1) ? (e<=3) : (t==3) ? (e>=1) : (t==4) ? (e>=2) : true;
}
__device__ inline bool mW3(int t, int e) {
  return (t==0) ? (e<=1) : (t==4) ? (e>=1) : true;
}

// ---------------- prep: scalars, 25x81 stencil table, fp16 weight packing ----------
__global__ void k_prep(const float* __restrict__ Ka, const float* __restrict__ Kw,
                       const float* __restrict__ miu,
                       const float* __restrict__ W1, const float* __restrict__ b1,
                       const float* __restrict__ W2, const float* __restrict__ W3,
                       float* __restrict__ tab, ushort* __restrict__ w2pk,
                       uint* __restrict__ w1pk, uint* __restrict__ b1pk,
                       ushort* __restrict__ w3fr, float* __restrict__ scal) {
  __shared__ float lka[25], lkw[36], lw1[288], lw3[288];
  int tid = threadIdx.x;   // 1024 threads
  if (tid < 192) scal[tid] = 0.f;
  if (tid < 25) lka[tid] = Ka[tid];
  if (tid < 36) lkw[tid] = Kw[tid];
  if (tid < 288) { lw1[tid] = W1[tid]; lw3[tid] = W3[tid]; }
  __syncthreads();
  const float mu = miu[0];
  #pragma unroll
  for (int k = 0; k < 2; k++) {
    int idx = tid + k*1024;
    if (idx < 2025) {
      int c = idx / 81, o = idx - c*81;
      int ty = c / 5, tx = c - 5*ty;
      int uy = o / 9 - 4, ux = o % 9 - 4;
      float s = 0.f;
      for (int ey = 0; ey < 5; ey++)
        for (int ex = 0; ex < 5; ex++) {
          int dy = ey + uy, dx = ex + ux;
          if (dy >= 0 && dy < 5 && dx >= 0 && dx < 5 && mA5(ty,ey) && mA5(tx,ex))
            s += lka[ey*5+ex] * lka[dy*5+dx];
        }
      float sw = 0.f;
      for (int ch = 0; ch < 4; ch++)
        for (int ey = 0; ey < 3; ey++)
          for (int ex = 0; ex < 3; ex++) {
            int dy = ey + uy, dx = ex + ux;
            if (dy >= 0 && dy < 3 && dx >= 0 && dx < 3 && mW3(ty,ey) && mW3(tx,ex))
              sw += lkw[ch*9+ey*3+ex] * lkw[ch*9+dy*3+dx];
          }
      tab[idx] = s + mu * sw;
    }
  }
  #pragma unroll
  for (int k = 0; k < 9; k++) {
    int i = tid + k*1024;
    int j = i & 7, l = (i >> 3) & 63, f = i >> 9;
    int t5 = f >> 1, h = f & 1;
    int co = 16*h + (l & 15), ci = 8*(l >> 4) + j;
    w2pk[i] = (ushort)(f2h2(W2[(co*32 + ci)*9 + t5], 0.f) & 0xffffu);
  }
  if (tid < 144) {
    int cp = tid / 9, t = tid % 9;
    w1pk[tid] = f2h2(lw1[(2*cp)*9 + t], lw1[(2*cp+1)*9 + t]);
  }
  if (tid < 16) b1pk[tid] = f2h2(b1[2*tid], b1[2*tid+1]);
  if (tid < 512) {
    int j = tid & 7, l = tid >> 3;
    int tap = l & 15, ch = 8*(l >> 4) + j;
    w3fr[tid] = (tap < 9) ? (ushort)(f2h2(lw3[ch*9 + tap], 0.f) & 0xffffu) : (ushort)0;
  }
}

// ---------------- fused CNN: xk = cnn(x), fp16/MFMA --------------------------------
// launch_bounds(512,2): allow ~256 VGPRs so the 72-VGPR afr[] A-fragment set stays
// register-resident across all 27 conv2 tasks (occupancy is LDS-limited anyway).
__launch_bounds__(512, 2)
__global__ void k_cnn(const float* __restrict__ x,
                      const ushort* __restrict__ w2pk, const uint* __restrict__ w1pk,
                      const uint* __restrict__ b1pk, const ushort* __restrict__ w3fr,
                      const float* __restrict__ b2, const float* __restrict__ b3,
                      float* __restrict__ xk) {
  __shared__ __align__(16) uint  h1u[7040];         // 20 x 352
  __shared__ __align__(16) uint  h2u[5472];         // 18 x 304; head doubles as xs
  uint* xs_h2 = h2u;

  const int tid = threadIdx.x;
  const int bimg = blockIdx.z;
  const int oy0 = blockIdx.y * 16, ox0 = blockIdx.x * 16;
  const float* xim = x + (size_t)bimg * IMG;

  for (int i = tid; i < 528; i += 512) {
    int ly = i / 24, lx = i % 24;
    int gy = oy0 + ly - 3, gx = ox0 + lx - 4;
    float v = 0.f;
    if ((unsigned)gy < HH && (unsigned)gx < WW) v = xim[gy*WW + gx];
    xs_h2[i] = f2h2(v, v);
  }
  __syncthreads();

  // ---- conv1 ----
  {
    const int cp = tid & 15;
    const int sg = tid >> 4;
    uint w1r[9];
    #pragma unroll
    for (int k = 0; k < 9; k++) w1r[k] = w1pk[cp*9 + k];
    const uint b1v = b1pk[cp];
    const int kg = cp >> 2, cl = cp & 3;
    #pragma unroll 1
    for (int s = sg; s < 100; s += 32) {
      int row = s / 5, st = s - 5*row;
      int px0 = st * 4;
      uint acc0 = b1v, acc1 = b1v, acc2 = b1v, acc3 = b1v;
      #pragma unroll
      for (int ky = 0; ky < 3; ky++) {
        int base = (row + ky) * 24 + px0;
        uint4 xa = *(const uint4*)&xs_h2[base];
        uint4 xb = *(const uint4*)&xs_h2[base + 4];
        uint xu[8] = {xa.x, xa.y, xa.z, xa.w, xb.x, xb.y, xb.z, xb.w};
        #pragma unroll
        for (int kx = 0; kx < 3; kx++) {
          uint w = w1r[ky*3 + kx];
          acc0 = pkfma(w, xu[1 + kx], acc0);
          acc1 = pkfma(w, xu[2 + kx], acc1);
          acc2 = pkfma(w, xu[3 + kx], acc2);
          acc3 = pkfma(w, xu[4 + kx], acc3);
        }
      }
      int Y = oy0 + row - 2;
      bool rin = (unsigned)Y < HH;
      int ob = row*352 + kg*88 + px0*4 + cl;
      #pragma unroll
      for (int i = 0; i < 4; i++) {
        int X = ox0 + px0 + i - 2;
        uint v = (rin && (unsigned)X < WW) ?
                 pkmax0(i == 0 ? acc0 : (i == 1 ? acc1 : (i == 2 ? acc2 : acc3))) : 0u;
        h1u[ob + i*4] = v;
      }
    }
  }
  __syncthreads();

  // ---- conv2 via MFMA f16 (A-frags register-resident) ----
  const int wv = tid >> 6, lane = tid & 63;
  const int nn = lane & 15, kg = lane >> 4;
  {
    half8 afr[9][2];
    #pragma unroll
    for (int t5 = 0; t5 < 9; t5++) {
      afr[t5][0] = ((const half8*)w2pk)[(t5*2 + 0)*64 + lane];
      afr[t5][1] = ((const half8*)w2pk)[(t5*2 + 1)*64 + lane];
    }
    float b2A[4], b2B[4];
    #pragma unroll
    for (int j = 0; j < 4; j++) { b2A[j] = b2[4*kg + j]; b2B[j] = b2[16 + 4*kg + j]; }

    #pragma unroll 1
    for (int t = wv; t < 27; t += 8) {
      int rp = t / 3, cs = t - 3*rp;
      int tx0 = (cs == 2) ? 10 : (cs << 3);
      int brow = 2*rp + (nn >> 3);
      int bcol = tx0 + (nn & 7);
      f32x4 accA = {0.f,0.f,0.f,0.f}, accB = {0.f,0.f,0.f,0.f};
      #pragma unroll
      for (int ky = 0; ky < 3; ky++)
        #pragma unroll
        for (int kx = 0; kx < 3; kx++) {
          const half8 bfr = *(const half8*)&h1u[(brow+ky)*352 + kg*88 + (bcol+kx)*4];
          accA = __builtin_amdgcn_mfma_f32_16x16x32_f16(afr[ky*3+kx][0], bfr, accA, 0, 0, 0);
          accB = __builtin_amdgcn_mfma_f32_16x16x32_f16(afr[ky*3+kx][1], bfr, accB, 0, 0, 0);
        }
      int gy = oy0 + brow - 1, gx = ox0 + bcol - 1;
      bool inb = ((unsigned)gy < HH) && ((unsigned)gx < WW);
      float v0 = inb ? fmaxf(accA[0] + b2A[0], 0.f) : 0.f;
      float v1 = inb ? fmaxf(accA[1] + b2A[1], 0.f) : 0.f;
      float v2 = inb ? fmaxf(accA[2] + b2A[2], 0.f) : 0.f;
      float v3 = inb ? fmaxf(accA[3] + b2A[3], 0.f) : 0.f;
      uint2 uA = make_uint2(f2h2(v0, v1), f2h2(v2, v3));
      v0 = inb ? fmaxf(accB[0] + b2B[0], 0.f) : 0.f;
      v1 = inb ? fmaxf(accB[1] + b2B[1], 0.f) : 0.f;
      v2 = inb ? fmaxf(accB[2] + b2B[2], 0.f) : 0.f;
      v3 = inb ? fmaxf(accB[3] + b2B[3], 0.f) : 0.f;
      uint2 uB = make_uint2(f2h2(v0, v1), f2h2(v2, v3));
      int base = brow*304 + bcol*4 + (kg & 1)*2;
      *(uint2*)&h2u[base + (kg >> 1)*76]       = uA;
      *(uint2*)&h2u[base + (2 + (kg >> 1))*76] = uB;
    }
  }
  __syncthreads();

  // ---- conv3 stage 1 via MFMA (Tlds aliased onto dead h1u) ----
  float* Tlds = (float*)h1u;
  {
    const half8 w3f = ((const half8*)w3fr)[lane];
    const int tap = nn;
    #pragma unroll 1
    for (int t = wv; t < 27; t += 8) {
      int rp = t / 3, cs = t - 3*rp;
      int tx0 = (cs == 2) ? 10 : (cs << 3);
      int ay = 2*rp + (nn >> 3);
      int ax = tx0 + (nn & 7);
      const half8 afrag = *(const half8*)&h2u[ay*304 + kg*76 + ax*4];
      f32x4 z = {0.f,0.f,0.f,0.f};
      f32x4 T4 = __builtin_amdgcn_mfma_f32_16x16x32_f16(afrag, w3f, z, 0, 0, 0);
      if (tap < 9) {
        int ty = 2*rp + (kg >> 1);
        int txb = tx0 + 4*(kg & 1);
        float* dst = &Tlds[ty*180 + tap*20 + txb];
        if (cs == 2) {
          dst[0] = T4[0]; dst[1] = T4[1]; dst[2] = T4[2]; dst[3] = T4[3];
        } else {
          *(f32x4*)dst = T4;
        }
      }
    }
  }
  __syncthreads();

  // ---- conv3 gather + residual ----
  {
    const int half = tid & 1, px = tid >> 1;
    const int oy = px >> 4, ox = px & 15;
    float s = 0.f;
    if (half == 0) {
      #pragma unroll
      for (int t = 0; t < 4; t++)
        s += Tlds[(oy + t/3)*180 + t*20 + (ox + t%3)];
    } else {
      #pragma unroll
      for (int t = 4; t < 9; t++)
        s += Tlds[(oy + t/3)*180 + t*20 + (ox + t%3)];
    }
    float other = __shfl_xor(s, 1, 64);
    if (half == 0) {
      float tot = s + other + b3[0] + xim[(size_t)(oy0+oy)*WW + ox0 + ox];
      xk[(size_t)bimg*IMG + (size_t)(oy0+oy)*WW + ox0 + ox] = tot;
    }
  }
}

// ---------------- M-apply: G-stencil + table-corrected boundary band ---------------
__device__ __forceinline__ void apply_M2(const float (*ssrc)[76], float* bandv,
    const float* Gs, const float* __restrict__ tab,
    int tid, int oy0, int ox0, float* accv) {
  const int sy = tid >> 3, sx0 = (tid & 7) * 8;
  #pragma unroll
  for (int k = 0; k < 8; k++) accv[k] = 0.f;
  #pragma unroll 1
  for (int oyy = 0; oyy < 9; oyy++) {
    float g[9];
    #pragma unroll
    for (int t = 0; t < 9; t++) g[t] = Gs[oyy*9+t];
    const float* row = &ssrc[sy+oyy][sx0];
    float4 r0 = *(const float4*)(row);
    float4 r1 = *(const float4*)(row+4);
    float4 r2 = *(const float4*)(row+8);
    float4 r3 = *(const float4*)(row+12);
    float v[16] = {r0.x,r0.y,r0.z,r0.w, r1.x,r1.y,r1.z,r1.w,
                   r2.x,r2.y,r2.z,r2.w, r3.x,r3.y,r3.z,r3.w};
    #pragma unroll
    for (int k = 0; k < 8; k++) {
      float a = accv[k];
      #pragma unroll
      for (int t = 0; t < 9; t++) a = fmaf(g[t], v[k+t], a);
      accv[k] = a;
    }
  }
  const int by = blockIdx.y, bx = blockIdx.x;
  const bool eT = (by == 0), eB = (by == (int)gridDim.y - 1);
  const bool eL = (bx == 0), eR = (bx == (int)gridDim.x - 1);
  if (eT | eB | eL | eR) {
    const int nTop = eT ? 128 : 0;
    const int nBot = eB ? 128 : 0;
    const int yl = eT ? 2 : 0, yh = eB ? 30 : 32;
    const int nL = eL ? 2*(yh-yl) : 0;
    const int nR = eR ? 2*(yh-yl) : 0;
    const int nBand = nTop + nBot + nL + nR;
    if (tid < nBand) {
      int i = tid, bsy, bsx;
      if (i < nTop) { bsy = i >> 6; bsx = i & 63; }
      else if (i < nTop + nBot) { i -= nTop; bsy = 30 + (i >> 6); bsx = i & 63; }
      else if (i < nTop + nBot + nL) { i -= nTop + nBot; bsy = yl + (i >> 1); bsx = i & 1; }
      else { i -= nTop + nBot + nL; bsy = yl + (i >> 1); bsx = 62 + (i & 1); }
      const int gy = oy0 + bsy, gx = ox0 + bsx;
      int ty = (gy == 0) ? 0 : (gy == 1) ? 1 : (gy == HH-1) ? 4 : (gy == HH-2) ? 3 : 2;
      int tx = (gx == 0) ? 0 : (gx == 1) ? 1 : (gx == WW-1) ? 4 : (gx == WW-2) ? 3 : 2;
      const float* S = tab + (ty*5 + tx)*81;
      float a = 0.f;
      #pragma unroll
      for (int oy = 0; oy < 9; oy++) {
        const float* r = &ssrc[bsy+oy][bsx];
        #pragma unroll
        for (int ox = 0; ox < 9; ox++) a = fmaf(S[oy*9+ox], r[ox], a);
      }
      bandv[tid] = a;
    }
    __syncthreads();
    #pragma unroll
    for (int k = 0; k < 8; k++) {
      const int sx = sx0 + k;
      const int gy = oy0 + sy, gx = ox0 + sx;
      if ((gy < 2) || (gy >= HH-2) || (gx < 2) || (gx >= WW-2)) {
        int idx;
        if (eT && sy < 2) idx = sy*64 + sx;
        else if (eB && sy >= 30) idx = nTop + (sy-30)*64 + sx;
        else if (eL && sx < 2) idx = nTop + nBot + (sy-yl)*2 + sx;
        else idx = nTop + nBot + nL + (sy-yl)*2 + (sx-62);
        accv[k] = bandv[idx];
      }
    }
  }
}

// ---------------- k_M0: fused rhs + r = M(xk) - rhs, p = -r, rtr reduction ---------
__launch_bounds__(256)
__global__ void k_M0(const float* __restrict__ xk, const float* __restrict__ sino,
                     const float* __restrict__ x,
                     float* __restrict__ outR, float* __restrict__ outP,
                     const float* __restrict__ tab,
                     const float* __restrict__ Ka, const float* __restrict__ Kw,
                     const float* __restrict__ laam, const float* __restrict__ miu,
                     float* __restrict__ rtrOut) {
  __shared__ __align__(16) float ssrc[40][76];
  __shared__ __align__(16) float tbuf[36][68];
  __shared__ __align__(16) float ssin[36][68];
  __shared__ __align__(16) float sx[36][68];
  __shared__ float Gs[81], kas[25], kws[36];
  __shared__ float red[4];
  const int tid = threadIdx.x;
  const int bimg = blockIdx.z;
  const int oy0 = blockIdx.y*32, ox0 = blockIdx.x*64;
  if (tid < 81) Gs[tid] = tab[972 + tid];
  if (tid >= 81 && tid < 106) kas[tid-81] = Ka[tid-81];
  if (tid >= 106 && tid < 142) kws[tid-106] = Kw[tid-106];
  const float mu = miu[0];
  const float lam = laam[0];
  const float* sxk = xk + (size_t)bimg*IMG;
  const float* ssi = sino + (size_t)bimg*IMG;
  const float* sxi = x + (size_t)bimg*IMG;

  for (int i = tid; i < 40*76; i += 256) {
    int ly = i/76, lx = i%76;
    int gy = oy0 + ly - 4, gx = ox0 + lx - 4;
    bool in = (lx < 72) && (gy >= 0 && gy < HH && gx >= 0 && gx < WW);
    ssrc[ly][lx] = in ? sxk[gy*WW+gx] : 0.f;
  }
  for (int i = tid; i < 36*68; i += 256) {
    int ly = i/68, lx = i%68;
    int gy = oy0 + ly - 2, gx = ox0 + lx - 2;
    bool in = (gy >= 0 && gy < HH && gx >= 0 && gx < WW);
    ssin[ly][lx] = in ? ssi[gy*WW+gx] : 0.f;
    sx[ly][lx]   = in ? sxi[gy*WW+gx] : 0.f;
  }
  __syncthreads();

  float accv[8];
  apply_M2(ssrc, &tbuf[0][0], Gs, tab, tid, oy0, ox0, accv);

  const int sy = tid >> 3, sx0 = (tid & 7) * 8;
  float rhsv[8];
  #pragma unroll
  for (int k = 0; k < 8; k++) rhsv[k] = 0.f;
  {
    #pragma unroll
    for (int dy = 0; dy < 5; dy++) {
      const float* row = &ssin[sy+4-dy][sx0];
      float4 r0 = *(const float4*)(row);
      float4 r1 = *(const float4*)(row+4);
      float4 r2 = *(const float4*)(row+8);
      float w[12] = {r0.x,r0.y,r0.z,r0.w, r1.x,r1.y,r1.z,r1.w, r2.x,r2.y,r2.z,r2.w};
      #pragma unroll
      for (int k = 0; k < 8; k++)
        #pragma unroll
        for (int dx = 0; dx < 5; dx++)
          rhsv[k] = fmaf(kas[dy*5+dx], w[k+4-dx], rhsv[k]);
    }
  }
  #pragma unroll 1
  for (int ch = 0; ch < 4; ch++) {
    __syncthreads();
    {
      float kw[9];
      #pragma unroll
      for (int k = 0; k < 9; k++) kw[k] = kws[ch*9 + k];
      #pragma unroll 1
      for (int item = tid; item < 2244; item += 256) {
        int dy = item / 66, dx = item - 66*dy;
        int gy = oy0 + dy - 1, gx = ox0 + dx - 1;
        float v = 0.f;
        if (gy >= 0 && gy < HH && gx >= 0 && gx < WW) {
          float wu = 0.f;
          #pragma unroll
          for (int e = 0; e < 9; e++) wu = fmaf(kw[e], sx[dy + e/3][dx + e%3], wu);
          v = fmaxf(wu - lam, 0.f) - fmaxf(-wu - lam, 0.f);
        }
        tbuf[dy][dx] = v;
      }
    }
    __syncthreads();
    {
      float kw[9];
      #pragma unroll
      for (int k = 0; k < 9; k++) kw[k] = mu * kws[ch*9 + k];
      #pragma unroll
      for (int dy = 0; dy < 3; dy++) {
        const float* row = &tbuf[sy+2-dy][sx0];
        float4 r0 = *(const float4*)(row);
        float4 r1 = *(const float4*)(row+4);
        float4 r2 = *(const float4*)(row+8);
        float w[12] = {r0.x,r0.y,r0.z,r0.w, r1.x,r1.y,r1.z,r1.w, r2.x,r2.y,r2.z,r2.w};
        #pragma unroll
        for (int k = 0; k < 8; k++)
          #pragma unroll
          for (int dx = 0; dx < 3; dx++)
            rhsv[k] = fmaf(kw[dy*3+dx], w[k+2-dx], rhsv[k]);
      }
    }
  }

  const int gy = oy0 + sy, gx0 = ox0 + sx0;
  float part = 0.f;
  #pragma unroll
  for (int k = 0; k < 8; k++) {
    size_t idx = (size_t)bimg*IMG + gy*WW + gx0 + k;
    float rv = accv[k] - rhsv[k];
    outR[idx] = rv;
    outP[idx] = -rv;
    part += rv*rv;
  }
  atomic_block_sum(part, red, &rtrOut[bimg]);
}

// ---------------- k_M: MODE 1 (q0 + den/rq/qq) -------------------------------------
template<int MODE>
__launch_bounds__(256)
__global__ void k_M(const float* __restrict__ srcA, const float* __restrict__ srcB,
                    float* __restrict__ outQ, float* __restrict__ outP,
                    const float* __restrict__ tab,
                    const float* __restrict__ beN, const float* __restrict__ beD,
                    float* __restrict__ acc, float* __restrict__ rqOut,
                    float* __restrict__ qqOut) {
  __shared__ __align__(16) float ssrc[40][76];
  __shared__ float bandv[256];
  __shared__ float Gs[81];
  __shared__ float red[12];
  const int tid = threadIdx.x;
  const int bimg = blockIdx.z;
  const int oy0 = blockIdx.y*32, ox0 = blockIdx.x*64;
  if (tid < 81) Gs[tid] = tab[972 + tid];
  float be = 0.f;
  if (MODE == 2) be = beN[bimg] / beD[bimg];
  const float* sA = srcA + (size_t)bimg*IMG;
  const float* sB = (MODE == 2) ? srcB + (size_t)bimg*IMG : nullptr;

  for (int i = tid; i < 40*76; i += 256) {
    int ly = i/76, lx = i%76;
    int gy = oy0 + ly - 4, gx = ox0 + lx - 4;
    bool in = (lx < 72) && (gy >= 0 && gy < HH && gx >= 0 && gx < WW);
    float v = 0.f;
    if (MODE == 2) {
      if (in) {
        v = -sA[gy*WW+gx] + be * sB[gy*WW+gx];
        if (ly >= 4 && ly < 36 && lx >= 4 && lx < 68)
          outP[(size_t)bimg*IMG + gy*WW + gx] = v;
      }
    } else {
      if (in) v = sA[gy*WW+gx];
    }
    ssrc[ly][lx] = v;
  }
  __syncthreads();

  float accv[8];
  apply_M2(ssrc, bandv, Gs, tab, tid, oy0, ox0, accv);

  const int sy = tid >> 3, sx0 = (tid & 7) * 8;
  const int gy = oy0 + sy, gx0 = ox0 + sx0;
  if (MODE == 1) {
    float pq = 0.f, qq = 0.f;
    #pragma unroll
    for (int k = 0; k < 8; k++) {
      size_t idx = (size_t)bimg*IMG + gy*WW + gx0 + k;
      float pv = ssrc[sy+4][sx0+4+k];
      float qv = accv[k];
      outQ[idx] = qv;
      pq += pv * qv;
      qq += qv * qv;
    }
    reduce3_atomic(pq, -pq, qq, red, &acc[bimg], rqOut ? &rqOut[bimg] : nullptr,
                   qqOut ? &qqOut[bimg] : nullptr);
  } else {
    float part = 0.f;
    #pragma unroll
    for (int k = 0; k < 8; k++) {
      size_t idx = (size_t)bimg*IMG + gy*WW + gx0 + k;
      float pv = ssrc[sy+4][sx0+4+k];
      outQ[idx] = accv[k];
      part += pv * accv[k];
    }
    atomic_block_sum(part, red, &acc[bimg]);
  }
}

// ---------------- fused CG iteration (scalar recurrence) ---------------------------
__launch_bounds__(256)
__global__ void k_it(float* __restrict__ xk,
                     const float* __restrict__ rold, float* __restrict__ rnew,
                     const float* __restrict__ pold, float* __restrict__ pnew,
                     const float* __restrict__ qold, float* __restrict__ qnew,
                     const float* __restrict__ tab,
                     float* __restrict__ scal, int it, int storeQ) {
  __shared__ __align__(16) float ssrc[40][76];
  __shared__ float rlds[2048];
  __shared__ float bandv[256];
  __shared__ float Gs[81];
  __shared__ float red[12];
  const int tid = threadIdx.x;
  const int bimg = blockIdx.z;
  const int oy0 = blockIdx.y*32, ox0 = blockIdx.x*64;
  if (tid < 81) Gs[tid] = tab[972 + tid];
  const float den_p = scal[       (it-1)*8 + bimg];
  const float rq_p  = scal[ 48 + (it-1)*8 + bimg];
  const float qq_p  = scal[ 96 + (it-1)*8 + bimg];
  const float rtr_p = scal[144 + (it-1)*8 + bimg];
  const float al = rtr_p / den_p;
  const float rtr_c = fmaf(al, fmaf(al, qq_p, 2.f*rq_p), rtr_p);
  const float be = rtr_c / rtr_p;
  if (tid == 0) scal[144 + it*8 + bimg] = rtr_c;
  const size_t ib = (size_t)bimg*IMG;

  for (int i = tid; i < 40*76; i += 256) {
    int ly = i/76, lx = i%76;
    int gy = oy0 + ly - 4, gx = ox0 + lx - 4;
    bool in = (lx < 72) && (gy >= 0 && gy < HH && gx >= 0 && gx < WW);
    float v = 0.f;
    if (in) {
      size_t g = ib + (size_t)gy*WW + gx;
      float pgv = pold[g];
      float rn = fmaf(al, qold[g], rold[g]);
      v = fmaf(be, pgv, -rn);
      if (ly >= 4 && ly < 36 && lx >= 4 && lx < 68) {
        pnew[g] = v;
        rnew[g] = rn;
        xk[g] = fmaf(al, pgv, xk[g]);
        rlds[(ly-4)*64 + (lx-4)] = rn;
      }
    }
    ssrc[ly][lx] = v;
  }
  __syncthreads();

  float accv[8];
  apply_M2(ssrc, bandv, Gs, tab, tid, oy0, ox0, accv);

  const int sy = tid >> 3, sx0 = (tid & 7) * 8;
  const int gy = oy0 + sy, gx0 = ox0 + sx0;
  float s_den = 0.f, s_rq = 0.f, s_qq = 0.f;
  #pragma unroll
  for (int k = 0; k < 8; k++) {
    size_t idx = ib + (size_t)gy*WW + gx0 + k;
    float qv = accv[k];
    float pv = ssrc[sy+4][sx0+4+k];
    float rv = rlds[sy*64 + sx0 + k];
    if (storeQ) qnew[idx] = qv;
    s_den += pv*qv;
    s_rq  += rv*qv;
    s_qq  += qv*qv;
  }
  reduce3_atomic(s_den, s_rq, s_qq, red, &scal[it*8+bimg], &scal[48+it*8+bimg],
                 &scal[96+it*8+bimg]);
}

__launch_bounds__(256)
__global__ void k_final(const float* __restrict__ xk, const float* __restrict__ p,
                        const float* __restrict__ num, const float* __restrict__ den,
                        float* __restrict__ out) {
  const int tid = threadIdx.x;
  const int bimg = blockIdx.x >> 8;
  const size_t idx4 = (size_t)blockIdx.x * 256 + tid;
  const float al = num[bimg] / den[bimg];
  float4 xv = ((const float4*)xk)[idx4];
  float4 pv = ((const float4*)p)[idx4];
  float4 o;
  o.x = xv.x + al*pv.x; o.y = xv.y + al*pv.y; o.z = xv.z + al*pv.z; o.w = xv.w + al*pv.w;
  ((float4*)out)[idx4] = o;
}

extern "C" void kernel_launch(void* const* d_in, const int* in_sizes, int n_in,
                              void* d_out, int out_size, void* d_ws, size_t ws_size,
                              hipStream_t stream) {
  const float* sino = (const float*)d_in[0];
  const float* x    = (const float*)d_in[1];
  const float* laam = (const float*)d_in[2];
  const float* miu  = (const float*)d_in[3];
  const float* Kw   = (const float*)d_in[4];
  const float* Ka   = (const float*)d_in[5];
  const float* W1   = (const float*)d_in[6];
  const float* b1   = (const float*)d_in[7];
  const float* W2   = (const float*)d_in[8];
  const float* b2   = (const float*)d_in[9];
  const float* W3   = (const float*)d_in[10];
  const float* b3   = (const float*)d_in[11];

  float* ws = (float*)d_ws;
  float* tail = ws + (size_t)6*NTOT;
  float* tab  = tail;                  // 2025 (pad 2048)
  float* scal = tail + 2048;           // 192: den[48] rq[48] qq[48] rtr[48]
  ushort* w2pk = (ushort*)(scal + 192);
  uint*   w1pk = (uint*)(w2pk + 9216);
  uint*   b1pk = w1pk + 144;
  ushort* w3fr = (ushort*)(b1pk + 16);
  float* dout = (float*)d_out;

  k_prep<<<1, 1024, 0, stream>>>(Ka, Kw, miu, W1, b1, W2, W3, tab, w2pk, w1pk,
                                 b1pk, w3fr, scal);

  float* xk = ws;
  k_cnn<<<dim3(32,32,8), 512, 0, stream>>>(x, w2pk, w1pk, b1pk, w3fr, b2, b3, xk);

  dim3 mg(8,16,8);
  float* rA = ws + (size_t)NTOT;
  float* rB = ws + 2*(size_t)NTOT;
  float* pA = ws + 3*(size_t)NTOT;
  float* pB = ws + 4*(size_t)NTOT;
  float* qB = ws + 5*(size_t)NTOT;
  float* qA = dout;
  k_M0<<<mg,256,0,stream>>>(xk, sino, x, rA, pA, tab, Ka, Kw, laam, miu, &scal[144]);
  k_M<1><<<mg,256,0,stream>>>(pA, nullptr, qA, nullptr, tab,
                              nullptr, nullptr, &scal[0], &scal[48], &scal[96]);
  float *rc=rA, *rn=rB, *pc=pA, *pn=pB, *qc=qA, *qn=qB;
  for (int it = 1; it <= 5; it++) {
    k_it<<<mg,256,0,stream>>>(xk, rc, rn, pc, pn, qc, qn, tab, scal,
                              it, it < 5 ? 1 : 0);
    float* t;
    t = rc; rc = rn; rn = t;
    t = pc; pc = pn; pn = t;
    t = qc; qc = qn; qn = t;
  }
  k_final<<<2048,256,0,stream>>>(xk, pc, &scal[144+40], &scal[40], dout);
}